// Round 8
// baseline (129.523 us; speedup 1.0000x reference)
//
#include <hip/hip_runtime.h>

// LoRA-DoRA fused linear for MI355X (gfx950).
// Shapes: x[256][4096] f32, W[11008][4096] f32, A[64][4096], B[11008][64],
//         M[1][4096], bias[11008]; out[256][11008] f32.
// Pipeline (no memsets, no global atomics):
//  K1: W_c = W + 2*(B@A) (bf16 MFMA per 128x128 tile) -> Wc bf16 (cacheable);
//      per-block column sum-of-squares -> part_ss[86][4096].
//      W reads NONTEMPORAL (streamed once; keep L3 for Wc/partK).
//  K2: scale = M/(sqrt(sum part_ss)+eps) fused with xs = bf16(x*scale).
//  K3: partK[kz] = xs @ Wc^T.  256x128 tile (full M -> each Wc element staged
//      exactly once), 512 thr, 8 waves (4m x 2n), KSPLIT=2 (172 blocks; same
//      compute makespan as KSPLIT=4's 2 rounds, but xs staging halves to
//      86 MB and partK round-trip halves to 22.5 MB), 32x32x16 MFMA,
//      XOR-swizzled LDS, single-buffer 2-barrier loop.
//  K4: out = partK[0]+partK[1] + bias (nontemporal partK reads).

typedef __attribute__((ext_vector_type(8))) short bf16x8;
typedef __attribute__((ext_vector_type(4))) float f32x4;
typedef __attribute__((ext_vector_type(16))) float f32x16;

#define OUT_DIM 11008
#define IN_DIM  4096
#define M_DIM   256
#define KSPLIT  2
#define NBLK_O  86   // OUT_DIM / 128

static __device__ __forceinline__ unsigned short f2bf(float f) {
  union { float f; unsigned u; } v; v.f = f;
  unsigned r = (v.u + 0x7fffu + ((v.u >> 16) & 1u)) >> 16;  // RNE
  return (unsigned short)r;
}
static __device__ __forceinline__ float bf2f(unsigned short h) {
  union { unsigned u; float f; } v; v.u = ((unsigned)h) << 16;
  return v.f;
}

#define GLOAD_LDS16(gptr, lptr)                                                        \
  __builtin_amdgcn_global_load_lds(                                                    \
      (const __attribute__((address_space(1))) unsigned int*)(gptr),                   \
      (__attribute__((address_space(3))) unsigned int*)(lptr), 16, 0, 0)

// ---------------------------------------------------------------------------
// K1: combine + column sumsq partials.  grid (IN/128=32, OUT/128=86), block 256.
// ---------------------------------------------------------------------------
__global__ __launch_bounds__(256) void k1_combine(
    const float* __restrict__ W,
    const float* __restrict__ lA,   // [64][4096]
    const float* __restrict__ lB,   // [11008][64]
    unsigned short* __restrict__ Wc,
    float* __restrict__ part_ss)    // [86][4096]
{
  const int i0 = blockIdx.x * 128;
  const int o0 = blockIdx.y * 128;
  const int tid = threadIdx.x;
  const int lane = tid & 63;
  const int wid = tid >> 6;
  const int wr = wid >> 1, wc = wid & 1;

  __shared__ unsigned short smem[2][128][72];  // [0]=A^T tile, [1]=B tile; reused as L / red
  // Stage A^T: At[c][r] = A[r][i0+c]  (bf16)
  for (int idx = tid; idx < 64 * 128; idx += 256) {
    const int r = idx >> 7, c = idx & 127;
    smem[0][c][r] = f2bf(lA[r * IN_DIM + i0 + c]);
  }
  // Stage B: Bt[o][r] = lB[o0+o][r]
  for (int idx = tid; idx < 128 * 64; idx += 256) {
    const int o = idx >> 6, r = idx & 63;
    smem[1][o][r] = f2bf(lB[(o0 + o) * 64 + r]);
  }
  __syncthreads();

  // l[128x128] = Bt(128x64) @ At(128x64)^T  via 16x16x32 bf16 MFMA
  f32x4 acc[4][4];
  #pragma unroll
  for (int a = 0; a < 4; ++a)
    #pragma unroll
    for (int b = 0; b < 4; ++b) acc[a][b] = (f32x4){0.f, 0.f, 0.f, 0.f};

  #pragma unroll
  for (int kk = 0; kk < 2; ++kk) {
    const int kofs = kk * 32 + (lane >> 4) * 8;
    bf16x8 af[4], bfr[4];
    #pragma unroll
    for (int mi = 0; mi < 4; ++mi)
      af[mi] = *reinterpret_cast<const bf16x8*>(&smem[1][wr * 64 + mi * 16 + (lane & 15)][kofs]);
    #pragma unroll
    for (int ni = 0; ni < 4; ++ni)
      bfr[ni] = *reinterpret_cast<const bf16x8*>(&smem[0][wc * 64 + ni * 16 + (lane & 15)][kofs]);
    #pragma unroll
    for (int mi = 0; mi < 4; ++mi)
      #pragma unroll
      for (int ni = 0; ni < 4; ++ni)
        acc[mi][ni] = __builtin_amdgcn_mfma_f32_16x16x32_bf16(af[mi], bfr[ni], acc[mi][ni], 0, 0, 0);
  }
  __syncthreads();

  // Spill l to LDS as bf16, row stride 136 (bank-friendly), overwriting At/Bt.
  unsigned short* L = &smem[0][0][0];
  #pragma unroll
  for (int mi = 0; mi < 4; ++mi) {
    const int ol = wr * 64 + mi * 16 + (lane >> 4) * 4;
    #pragma unroll
    for (int ni = 0; ni < 4; ++ni) {
      const int il = wc * 64 + ni * 16 + (lane & 15);
      #pragma unroll
      for (int j = 0; j < 4; ++j)
        L[(ol + j) * 136 + il] = f2bf(acc[mi][ni][j]);
    }
  }
  __syncthreads();

  // Combine phase: nontemporal f32x4 reads of W (streamed once — keep L3
  // for Wc/partK), bf16x4 writes of W_c (cacheable), sumsq accum.
  const int c4 = (tid & 31) * 4;  // column chunk (fixed per thread)
  const int r0 = tid >> 5;        // 0..7
  float sq0 = 0.f, sq1 = 0.f, sq2 = 0.f, sq3 = 0.f;
  #pragma unroll
  for (int it = 0; it < 16; ++it) {
    const int rr = r0 + it * 8;
    const size_t go = (size_t)(o0 + rr) * IN_DIM + i0 + c4;
    const f32x4 w = __builtin_nontemporal_load(reinterpret_cast<const f32x4*>(&W[go]));
    const unsigned short* lp = &L[rr * 136 + c4];
    const float w0 = w[0] + 2.f * bf2f(lp[0]);
    const float w1 = w[1] + 2.f * bf2f(lp[1]);
    const float w2 = w[2] + 2.f * bf2f(lp[2]);
    const float w3 = w[3] + 2.f * bf2f(lp[3]);
    sq0 += w0 * w0; sq1 += w1 * w1; sq2 += w2 * w2; sq3 += w3 * w3;
    ushort4 o4 = make_ushort4(f2bf(w0), f2bf(w1), f2bf(w2), f2bf(w3));
    *reinterpret_cast<ushort4*>(&Wc[go]) = o4;
  }
  __syncthreads();
  float* red = reinterpret_cast<float*>(L);  // 256*4 floats
  red[((r0 << 5) | (tid & 31)) * 4 + 0] = sq0;
  red[((r0 << 5) | (tid & 31)) * 4 + 1] = sq1;
  red[((r0 << 5) | (tid & 31)) * 4 + 2] = sq2;
  red[((r0 << 5) | (tid & 31)) * 4 + 3] = sq3;
  __syncthreads();
  if (tid < 128) {
    const int cc = tid >> 2, k = tid & 3;
    float s = 0.f;
    #pragma unroll
    for (int g = 0; g < 8; ++g) s += red[(((g << 5) | cc) << 2) + k];
    part_ss[(size_t)blockIdx.y * IN_DIM + i0 + tid] = s;
  }
}

// ---------------------------------------------------------------------------
// K2: fused scale + xs.  grid (16, 16), block 256.
// ---------------------------------------------------------------------------
__global__ __launch_bounds__(256) void k2_xs(
    const float* __restrict__ x, const float* __restrict__ lM,
    const float* __restrict__ part_ss, unsigned short* __restrict__ xs)
{
  const int i = blockIdx.x * 256 + threadIdx.x;  // column
  const int b0 = blockIdx.y * 16;
  float s = 0.f;
  #pragma unroll 2
  for (int b = 0; b < NBLK_O; ++b) s += part_ss[(size_t)b * IN_DIM + i];
  const float sc = lM[i] / (sqrtf(s) + 1e-6f);
  #pragma unroll 4
  for (int r = 0; r < 16; ++r) {
    const size_t o = (size_t)(b0 + r) * IN_DIM + i;
    xs[o] = f2bf(x[o] * sc);
  }
}

// ---------------------------------------------------------------------------
// K3: partK[kz] = xs @ Wc^T over K-half.  grid (86, KSPLIT=2), block 512.
// 256x128 output tile (full M): each Wc element staged EXACTLY ONCE; xs
// staged once per (n-tile, kz) = 86 MB total.  8 waves (4m x 2n), BK=64,
// 32x32x16 MFMA, XOR-swizzled LDS, single-buffer 2-barrier loop.
// ---------------------------------------------------------------------------
__global__ __launch_bounds__(512) void k3_gemm(
    const unsigned short* __restrict__ xs,  // [256][4096] bf16
    const unsigned short* __restrict__ Wc,  // [11008][4096] bf16
    float* __restrict__ partK)              // [KSPLIT][256][11008] f32
{
  const int n0 = blockIdx.x * 128;
  const int kz = blockIdx.y;
  const int tid = threadIdx.x;
  const int lane = tid & 63;
  const int wid = tid >> 6;      // 0..7
  const int wm = wid >> 1;       // 0..3 -> m-base = wm*64
  const int wn = wid & 1;        // 0..1 -> n-base = wn*64

  __shared__ unsigned short As[256 * 64];   // 32 KB
  __shared__ unsigned short Bs[128 * 64];   // 16 KB

  f32x16 acc[2][2];
  #pragma unroll
  for (int a = 0; a < 2; ++a)
    #pragma unroll
    for (int b = 0; b < 2; ++b)
      #pragma unroll
      for (int r = 0; r < 16; ++r) acc[a][b][r] = 0.f;

  const int k0base = kz * (IN_DIM / KSPLIT);
  const int srow = tid >> 3;        // 0..63
  const int g    = tid & 7;         // 16B granule within 64-col row
  const int gc   = (g ^ (srow & 7)) * 8;  // pre-swizzled source col (row&7 == srow&7)
  const int ldst = srow * 64 + g * 8;

  for (int ks = 0; ks < (IN_DIM / KSPLIT) / 64; ++ks) {  // 32 steps
    const int k0 = k0base + ks * 64;
    #pragma unroll
    for (int iss = 0; iss < 4; ++iss)   // xs rows srow + 64*iss  (0..255)
      GLOAD_LDS16(&xs[(size_t)(srow + 64 * iss) * IN_DIM + k0 + gc],
                  &As[iss * 64 * 64 + ldst]);
    #pragma unroll
    for (int iss = 0; iss < 2; ++iss)   // Wc rows n0 + srow + 64*iss (0..127)
      GLOAD_LDS16(&Wc[(size_t)(n0 + srow + 64 * iss) * IN_DIM + k0 + gc],
                  &Bs[iss * 64 * 64 + ldst]);
    __syncthreads();  // drains vmcnt (compiler-inserted)
    #pragma unroll
    for (int kk = 0; kk < 4; ++kk) {
      const int kb = kk * 16 + (lane >> 5) * 8;  // bf16 k-offset for this lane
      bf16x8 af[2], bfr[2];
      #pragma unroll
      for (int mi = 0; mi < 2; ++mi) {
        const int Ra = wm * 64 + mi * 32 + (lane & 31);
        af[mi] = *reinterpret_cast<const bf16x8*>(&As[Ra * 64 + (kb ^ ((Ra & 7) << 3))]);
      }
      #pragma unroll
      for (int ni = 0; ni < 2; ++ni) {
        const int Rb = wn * 64 + ni * 32 + (lane & 31);
        bfr[ni] = *reinterpret_cast<const bf16x8*>(&Bs[Rb * 64 + (kb ^ ((Rb & 7) << 3))]);
      }
      #pragma unroll
      for (int mi = 0; mi < 2; ++mi)
        #pragma unroll
        for (int ni = 0; ni < 2; ++ni)
          acc[mi][ni] = __builtin_amdgcn_mfma_f32_32x32x16_bf16(af[mi], bfr[ni], acc[mi][ni], 0, 0, 0);
    }
    __syncthreads();
  }

  // Epilogue: plain stores.  32x32 C/D layout: col=lane&31,
  // row=(reg&3)+8*(reg>>2)+4*(lane>>5)  [m74/m101-verified].
  float* __restrict__ pk = partK + (size_t)kz * ((size_t)M_DIM * OUT_DIM);
  const int hi = lane >> 5;
  const int cl = lane & 31;
  #pragma unroll
  for (int mi = 0; mi < 2; ++mi) {
    #pragma unroll
    for (int ni = 0; ni < 2; ++ni) {
      const int colb = n0 + wn * 64 + ni * 32 + cl;
      #pragma unroll
      for (int q = 0; q < 4; ++q) {
        const int rowb = wm * 64 + mi * 32 + q * 8 + hi * 4;
        #pragma unroll
        for (int j = 0; j < 4; ++j)
          pk[(size_t)(rowb + j) * OUT_DIM + colb] = acc[mi][ni][q * 4 + j];
      }
    }
  }
}

// ---------------------------------------------------------------------------
// K4: out = partK[0] + partK[1] + bias.  grid 2752, block 256, f32x4/thread.
// partK reads nontemporal (consumed once, never re-read).
// ---------------------------------------------------------------------------
__global__ __launch_bounds__(256) void k4_reduce(
    const float* __restrict__ partK, const float* __restrict__ bias,
    float* __restrict__ out)
{
  const size_t idx = ((size_t)blockIdx.x * 256 + threadIdx.x) * 4;
  const int col = (int)(idx % OUT_DIM);
  const size_t stride = (size_t)M_DIM * OUT_DIM;
  f32x4 s = __builtin_nontemporal_load(reinterpret_cast<const f32x4*>(&partK[idx]));
  #pragma unroll
  for (int kz = 1; kz < KSPLIT; ++kz) {
    const f32x4 p = __builtin_nontemporal_load(
        reinterpret_cast<const f32x4*>(&partK[kz * stride + idx]));
    s += p;
  }
  const f32x4 bv = *reinterpret_cast<const f32x4*>(&bias[col]);
  s += bv;
  *reinterpret_cast<f32x4*>(&out[idx]) = s;
}

// ---------------------------------------------------------------------------
extern "C" void kernel_launch(void* const* d_in, const int* in_sizes, int n_in,
                              void* d_out, int out_size, void* d_ws, size_t ws_size,
                              hipStream_t stream) {
  const float* x    = (const float*)d_in[0];
  const float* W    = (const float*)d_in[1];
  const float* lA   = (const float*)d_in[2];
  const float* lB   = (const float*)d_in[3];
  const float* lM   = (const float*)d_in[4];
  const float* bias = (const float*)d_in[5];
  float* out = (float*)d_out;

  // Workspace layout (~116.3 MB total):
  //   Wc      bf16 [11008*4096]      @ 0          (90,177,536 B)
  //   xs      bf16 [256*4096]        @ 90,177,536 ( 2,097,152 B)
  //   part_ss f32  [86][4096]        @ 92,291,072 ( 1,409,024 B)
  //   partK   f32  [2][256][11008]   @ 93,700,096 (22,544,384 B)
  char* ws = (char*)d_ws;
  unsigned short* Wc   = (unsigned short*)(ws);
  unsigned short* xs   = (unsigned short*)(ws + 90177536u);
  float* part_ss       = (float*)(ws + 92291072u);
  float* partK         = (float*)(ws + 93700096u);

  k1_combine<<<dim3(IN_DIM / 128, NBLK_O), 256, 0, stream>>>(W, lA, lB, Wc, part_ss);
  k2_xs<<<dim3(IN_DIM / 256, M_DIM / 16), 256, 0, stream>>>(x, lM, part_ss, xs);
  k3_gemm<<<dim3(NBLK_O, KSPLIT), 512, 0, stream>>>(xs, Wc, partK);
  k4_reduce<<<dim3((M_DIM * OUT_DIM) / 1024), 256, 0, stream>>>(partK, bias, out);
}

// Round 9
// 116.953 us; speedup vs baseline: 1.1075x; 1.1075x over previous
//
#include <hip/hip_runtime.h>

// LoRA-DoRA fused linear for MI355X (gfx950).
// Shapes: x[256][4096] f32, W[11008][4096] f32, A[64][4096], B[11008][64],
//         M[1][4096], bias[11008]; out[256][11008] f32.
// Pipeline (no memsets, no global atomics):
//  K1: W_c = W + 2*(B@A) (bf16 MFMA per 128x128 tile) -> Wc bf16 (cacheable);
//      per-block column sum-of-squares -> part_ss[86][4096].
//      W reads NONTEMPORAL; combine-phase LDS reads vectorized (ds_read_b64).
//  K2: scale = M/(sqrt(sum part_ss)+eps) fused with xs = bf16(x*scale).
//  K3: partK[kz] = xs @ Wc^T.  256x128 tile (full M -> each Wc element staged
//      exactly once), 512 thr, 8 waves (4m x 2n), KSPLIT=4 (344 blocks;
//      measured best vs 2/8), 32x32x16 MFMA, XOR-swizzled LDS, single-buffer
//      2-barrier loop.  Partials stored BF16 (R7-verified absmax-neutral).
//  K4: out = sum_kz bf2f(partK[kz]) + bias (nontemporal partK reads).

typedef __attribute__((ext_vector_type(8))) short bf16x8;
typedef __attribute__((ext_vector_type(4))) float f32x4;
typedef __attribute__((ext_vector_type(16))) float f32x16;
typedef __attribute__((ext_vector_type(4))) unsigned short u16x4;

#define OUT_DIM 11008
#define IN_DIM  4096
#define M_DIM   256
#define KSPLIT  4
#define NBLK_O  86   // OUT_DIM / 128

static __device__ __forceinline__ unsigned short f2bf(float f) {
  union { float f; unsigned u; } v; v.f = f;
  unsigned r = (v.u + 0x7fffu + ((v.u >> 16) & 1u)) >> 16;  // RNE
  return (unsigned short)r;
}
static __device__ __forceinline__ float bf2f(unsigned short h) {
  union { unsigned u; float f; } v; v.u = ((unsigned)h) << 16;
  return v.f;
}

#define GLOAD_LDS16(gptr, lptr)                                                        \
  __builtin_amdgcn_global_load_lds(                                                    \
      (const __attribute__((address_space(1))) unsigned int*)(gptr),                   \
      (__attribute__((address_space(3))) unsigned int*)(lptr), 16, 0, 0)

// ---------------------------------------------------------------------------
// K1: combine + column sumsq partials.  grid (IN/128=32, OUT/128=86), block 256.
// ---------------------------------------------------------------------------
__global__ __launch_bounds__(256) void k1_combine(
    const float* __restrict__ W,
    const float* __restrict__ lA,   // [64][4096]
    const float* __restrict__ lB,   // [11008][64]
    unsigned short* __restrict__ Wc,
    float* __restrict__ part_ss)    // [86][4096]
{
  const int i0 = blockIdx.x * 128;
  const int o0 = blockIdx.y * 128;
  const int tid = threadIdx.x;
  const int lane = tid & 63;
  const int wid = tid >> 6;
  const int wr = wid >> 1, wc = wid & 1;

  __shared__ unsigned short smem[2][128][72];  // [0]=A^T tile, [1]=B tile; reused as L / red
  // Stage A^T: At[c][r] = A[r][i0+c]  (bf16)
  for (int idx = tid; idx < 64 * 128; idx += 256) {
    const int r = idx >> 7, c = idx & 127;
    smem[0][c][r] = f2bf(lA[r * IN_DIM + i0 + c]);
  }
  // Stage B: Bt[o][r] = lB[o0+o][r]
  for (int idx = tid; idx < 128 * 64; idx += 256) {
    const int o = idx >> 6, r = idx & 63;
    smem[1][o][r] = f2bf(lB[(o0 + o) * 64 + r]);
  }
  __syncthreads();

  // l[128x128] = Bt(128x64) @ At(128x64)^T  via 16x16x32 bf16 MFMA
  f32x4 acc[4][4];
  #pragma unroll
  for (int a = 0; a < 4; ++a)
    #pragma unroll
    for (int b = 0; b < 4; ++b) acc[a][b] = (f32x4){0.f, 0.f, 0.f, 0.f};

  #pragma unroll
  for (int kk = 0; kk < 2; ++kk) {
    const int kofs = kk * 32 + (lane >> 4) * 8;
    bf16x8 af[4], bfr[4];
    #pragma unroll
    for (int mi = 0; mi < 4; ++mi)
      af[mi] = *reinterpret_cast<const bf16x8*>(&smem[1][wr * 64 + mi * 16 + (lane & 15)][kofs]);
    #pragma unroll
    for (int ni = 0; ni < 4; ++ni)
      bfr[ni] = *reinterpret_cast<const bf16x8*>(&smem[0][wc * 64 + ni * 16 + (lane & 15)][kofs]);
    #pragma unroll
    for (int mi = 0; mi < 4; ++mi)
      #pragma unroll
      for (int ni = 0; ni < 4; ++ni)
        acc[mi][ni] = __builtin_amdgcn_mfma_f32_16x16x32_bf16(af[mi], bfr[ni], acc[mi][ni], 0, 0, 0);
  }
  __syncthreads();

  // Spill l to LDS as bf16, row stride 136 (bank-friendly), overwriting At/Bt.
  unsigned short* L = &smem[0][0][0];
  #pragma unroll
  for (int mi = 0; mi < 4; ++mi) {
    const int ol = wr * 64 + mi * 16 + (lane >> 4) * 4;
    #pragma unroll
    for (int ni = 0; ni < 4; ++ni) {
      const int il = wc * 64 + ni * 16 + (lane & 15);
      #pragma unroll
      for (int j = 0; j < 4; ++j)
        L[(ol + j) * 136 + il] = f2bf(acc[mi][ni][j]);
    }
  }
  __syncthreads();

  // Combine phase: nontemporal f32x4 reads of W (streamed once — keep L3
  // for Wc/partK), ds_read_b64 of L, bf16x4 writes of W_c, sumsq accum.
  const int c4 = (tid & 31) * 4;  // column chunk (fixed per thread)
  const int r0 = tid >> 5;        // 0..7
  float sq0 = 0.f, sq1 = 0.f, sq2 = 0.f, sq3 = 0.f;
  #pragma unroll
  for (int it = 0; it < 16; ++it) {
    const int rr = r0 + it * 8;
    const size_t go = (size_t)(o0 + rr) * IN_DIM + i0 + c4;
    const f32x4 w = __builtin_nontemporal_load(reinterpret_cast<const f32x4*>(&W[go]));
    const u16x4 lv = *reinterpret_cast<const u16x4*>(&L[rr * 136 + c4]);  // 8B-aligned
    const float w0 = w[0] + 2.f * bf2f(lv[0]);
    const float w1 = w[1] + 2.f * bf2f(lv[1]);
    const float w2 = w[2] + 2.f * bf2f(lv[2]);
    const float w3 = w[3] + 2.f * bf2f(lv[3]);
    sq0 += w0 * w0; sq1 += w1 * w1; sq2 += w2 * w2; sq3 += w3 * w3;
    u16x4 o4 = {f2bf(w0), f2bf(w1), f2bf(w2), f2bf(w3)};
    *reinterpret_cast<u16x4*>(&Wc[go]) = o4;
  }
  __syncthreads();
  float* red = reinterpret_cast<float*>(L);  // 256*4 floats
  red[((r0 << 5) | (tid & 31)) * 4 + 0] = sq0;
  red[((r0 << 5) | (tid & 31)) * 4 + 1] = sq1;
  red[((r0 << 5) | (tid & 31)) * 4 + 2] = sq2;
  red[((r0 << 5) | (tid & 31)) * 4 + 3] = sq3;
  __syncthreads();
  if (tid < 128) {
    const int cc = tid >> 2, k = tid & 3;
    float s = 0.f;
    #pragma unroll
    for (int g = 0; g < 8; ++g) s += red[(((g << 5) | cc) << 2) + k];
    part_ss[(size_t)blockIdx.y * IN_DIM + i0 + tid] = s;
  }
}

// ---------------------------------------------------------------------------
// K2: fused scale + xs.  grid (16, 16), block 256.
// ---------------------------------------------------------------------------
__global__ __launch_bounds__(256) void k2_xs(
    const float* __restrict__ x, const float* __restrict__ lM,
    const float* __restrict__ part_ss, unsigned short* __restrict__ xs)
{
  const int i = blockIdx.x * 256 + threadIdx.x;  // column
  const int b0 = blockIdx.y * 16;
  float s = 0.f;
  #pragma unroll 2
  for (int b = 0; b < NBLK_O; ++b) s += part_ss[(size_t)b * IN_DIM + i];
  const float sc = lM[i] / (sqrtf(s) + 1e-6f);
  #pragma unroll 4
  for (int r = 0; r < 16; ++r) {
    const size_t o = (size_t)(b0 + r) * IN_DIM + i;
    xs[o] = f2bf(x[o] * sc);
  }
}

// ---------------------------------------------------------------------------
// K3: partK[kz] = xs @ Wc^T over K-quarter.  grid (86, KSPLIT=4), block 512.
// 256x128 output tile (full M): each Wc element staged EXACTLY ONCE.
// 8 waves (4m x 2n), BK=64, 32x32x16 MFMA, XOR-swizzled LDS, single-buffer
// 2-barrier loop.  BF16 partial stores (R7-verified absmax-neutral).
// ---------------------------------------------------------------------------
__global__ __launch_bounds__(512) void k3_gemm(
    const unsigned short* __restrict__ xs,  // [256][4096] bf16
    const unsigned short* __restrict__ Wc,  // [11008][4096] bf16
    unsigned short* __restrict__ partK)     // [KSPLIT][256][11008] bf16
{
  const int n0 = blockIdx.x * 128;
  const int kz = blockIdx.y;
  const int tid = threadIdx.x;
  const int lane = tid & 63;
  const int wid = tid >> 6;      // 0..7
  const int wm = wid >> 1;       // 0..3 -> m-base = wm*64
  const int wn = wid & 1;        // 0..1 -> n-base = wn*64

  __shared__ unsigned short As[256 * 64];   // 32 KB
  __shared__ unsigned short Bs[128 * 64];   // 16 KB

  f32x16 acc[2][2];
  #pragma unroll
  for (int a = 0; a < 2; ++a)
    #pragma unroll
    for (int b = 0; b < 2; ++b)
      #pragma unroll
      for (int r = 0; r < 16; ++r) acc[a][b][r] = 0.f;

  const int k0base = kz * (IN_DIM / KSPLIT);
  const int srow = tid >> 3;        // 0..63
  const int g    = tid & 7;         // 16B granule within 64-col row
  const int gc   = (g ^ (srow & 7)) * 8;  // pre-swizzled source col (row&7 == srow&7)
  const int ldst = srow * 64 + g * 8;

  for (int ks = 0; ks < (IN_DIM / KSPLIT) / 64; ++ks) {  // 16 steps
    const int k0 = k0base + ks * 64;
    #pragma unroll
    for (int iss = 0; iss < 4; ++iss)   // xs rows srow + 64*iss  (0..255)
      GLOAD_LDS16(&xs[(size_t)(srow + 64 * iss) * IN_DIM + k0 + gc],
                  &As[iss * 64 * 64 + ldst]);
    #pragma unroll
    for (int iss = 0; iss < 2; ++iss)   // Wc rows n0 + srow + 64*iss (0..127)
      GLOAD_LDS16(&Wc[(size_t)(n0 + srow + 64 * iss) * IN_DIM + k0 + gc],
                  &Bs[iss * 64 * 64 + ldst]);
    __syncthreads();  // drains vmcnt (compiler-inserted)
    #pragma unroll
    for (int kk = 0; kk < 4; ++kk) {
      const int kb = kk * 16 + (lane >> 5) * 8;  // bf16 k-offset for this lane
      bf16x8 af[2], bfr[2];
      #pragma unroll
      for (int mi = 0; mi < 2; ++mi) {
        const int Ra = wm * 64 + mi * 32 + (lane & 31);
        af[mi] = *reinterpret_cast<const bf16x8*>(&As[Ra * 64 + (kb ^ ((Ra & 7) << 3))]);
      }
      #pragma unroll
      for (int ni = 0; ni < 2; ++ni) {
        const int Rb = wn * 64 + ni * 32 + (lane & 31);
        bfr[ni] = *reinterpret_cast<const bf16x8*>(&Bs[Rb * 64 + (kb ^ ((Rb & 7) << 3))]);
      }
      #pragma unroll
      for (int mi = 0; mi < 2; ++mi)
        #pragma unroll
        for (int ni = 0; ni < 2; ++ni)
          acc[mi][ni] = __builtin_amdgcn_mfma_f32_32x32x16_bf16(af[mi], bfr[ni], acc[mi][ni], 0, 0, 0);
    }
    __syncthreads();
  }

  // Epilogue: bf16 stores.  32x32 C/D layout: col=lane&31,
  // row=(reg&3)+8*(reg>>2)+4*(lane>>5)  [m74/m101-verified].
  unsigned short* __restrict__ pk = partK + (size_t)kz * ((size_t)M_DIM * OUT_DIM);
  const int hi = lane >> 5;
  const int cl = lane & 31;
  #pragma unroll
  for (int mi = 0; mi < 2; ++mi) {
    #pragma unroll
    for (int ni = 0; ni < 2; ++ni) {
      const int colb = n0 + wn * 64 + ni * 32 + cl;
      #pragma unroll
      for (int q = 0; q < 4; ++q) {
        const int rowb = wm * 64 + mi * 32 + q * 8 + hi * 4;
        #pragma unroll
        for (int j = 0; j < 4; ++j)
          pk[(size_t)(rowb + j) * OUT_DIM + colb] = f2bf(acc[mi][ni][q * 4 + j]);
      }
    }
  }
}

// ---------------------------------------------------------------------------
// K4: out = sum_kz bf2f(partK[kz]) + bias.  grid 2752, block 256, 4 out/thread.
// partK reads nontemporal (consumed once, never re-read).
// ---------------------------------------------------------------------------
__global__ __launch_bounds__(256) void k4_reduce(
    const unsigned short* __restrict__ partK, const float* __restrict__ bias,
    float* __restrict__ out)
{
  const size_t idx = ((size_t)blockIdx.x * 256 + threadIdx.x) * 4;
  const int col = (int)(idx % OUT_DIM);
  const size_t stride = (size_t)M_DIM * OUT_DIM;
  f32x4 s = *reinterpret_cast<const f32x4*>(&bias[col]);
  #pragma unroll
  for (int kz = 0; kz < KSPLIT; ++kz) {
    const u16x4 p = __builtin_nontemporal_load(
        reinterpret_cast<const u16x4*>(&partK[kz * stride + idx]));
    s[0] += bf2f(p[0]); s[1] += bf2f(p[1]); s[2] += bf2f(p[2]); s[3] += bf2f(p[3]);
  }
  *reinterpret_cast<f32x4*>(&out[idx]) = s;
}

// ---------------------------------------------------------------------------
extern "C" void kernel_launch(void* const* d_in, const int* in_sizes, int n_in,
                              void* d_out, int out_size, void* d_ws, size_t ws_size,
                              hipStream_t stream) {
  const float* x    = (const float*)d_in[0];
  const float* W    = (const float*)d_in[1];
  const float* lA   = (const float*)d_in[2];
  const float* lB   = (const float*)d_in[3];
  const float* lM   = (const float*)d_in[4];
  const float* bias = (const float*)d_in[5];
  float* out = (float*)d_out;

  // Workspace layout (~116.3 MB total):
  //   Wc      bf16 [11008*4096]      @ 0          (90,177,536 B)
  //   xs      bf16 [256*4096]        @ 90,177,536 ( 2,097,152 B)
  //   part_ss f32  [86][4096]        @ 92,291,072 ( 1,409,024 B)
  //   partK   bf16 [4][256][11008]   @ 93,700,096 (22,544,384 B)
  char* ws = (char*)d_ws;
  unsigned short* Wc    = (unsigned short*)(ws);
  unsigned short* xs    = (unsigned short*)(ws + 90177536u);
  float* part_ss        = (float*)(ws + 92291072u);
  unsigned short* partK = (unsigned short*)(ws + 93700096u);

  k1_combine<<<dim3(IN_DIM / 128, NBLK_O), 256, 0, stream>>>(W, lA, lB, Wc, part_ss);
  k2_xs<<<dim3(IN_DIM / 256, M_DIM / 16), 256, 0, stream>>>(x, lM, part_ss, xs);
  k3_gemm<<<dim3(NBLK_O, KSPLIT), 512, 0, stream>>>(xs, Wc, partK);
  k4_reduce<<<dim3((M_DIM * OUT_DIM) / 1024), 256, 0, stream>>>(partK, bias, out);
}